// Round 10
// baseline (209.816 us; speedup 1.0000x reference)
//
#include <hip/hip_runtime.h>
#include <hip/hip_fp16.h>
#include <math.h>

#define HH 512
#define WW 512
#define BB 4
#define NPIX (BB * HH * WW)

#define HS 4                  // core rows per wave
#define NSX 10                // strips of 56 core cols (10*56=560 >= 512)
#define NBAND (HH / HS)       // 128
#define NWAVES (NSX * NBAND * BB)   // 5120
#define NBLK (NWAVES / 4)           // 1280

constexpr float TAUf   = 0.01f;
constexpr float RHOf   = 1.99f;
constexpr float SIGMAf = (float)(1.0 / 0.01 / 72.0);
constexpr float INV1PT = (float)(1.0 / 1.01);

__device__ __forceinline__ float cf(__half h) { return __half2float(h); }
__device__ __forceinline__ float SD(float v)  { return __shfl_down(v, 1, 64); } // lane+1
__device__ __forceinline__ float SUp(float v) { return __shfl_up(v, 1, 64); }   // lane-1

// Two fused primal-dual iterations per launch, register-ring pipeline.
// Step k processes: unpk u(r+1) | i(r) | s,t(r) | u'(r-2) | i'(r-3) | s',t'(r-3) | u''(r-5)
// with r = R0 - 5 + k.  Ring slot of a row = (step it was produced) & mask; all
// slots fold to constants under full unroll.
// MODE: 0 = iters 0+1 (iter0 analytic: x=y, r=0, u=0); 1 = mid pair; 2 = iters 8+9 (x-only out)
template <int MODE>
__global__ __launch_bounds__(256) void sweep2(
    const float* __restrict__ y, const int* __restrict__ ths_p,
    const __half* __restrict__ x2_in, const __half* __restrict__ r2_in,
    const __half* __restrict__ u_in,
    __half* __restrict__ x2_out, __half* __restrict__ r2_out,
    __half* __restrict__ u_out, float* __restrict__ xout)
{
    const int tid  = threadIdx.x;
    const int lane = tid & 63;
    const int wid  = blockIdx.x * 4 + (tid >> 6);
    const int sx   = wid % NSX;
    const int t2   = wid / NSX;
    const int band = t2 & (NBAND - 1);
    const int b    = t2 / NBAND;
    const int R0   = band * HS;
    const int w    = sx * 56 - 4 + lane;
    const int boff = b * (HH * WW);
    const bool wok = ((unsigned)w) < (unsigned)WW;
    const float mA = (w >= 1 && w < WW) ? 1.f : 0.f;       // (w>=1)
    const float mB = (w >= 0 && w < WW - 1) ? 1.f : 0.f;   // (w<W-1)
    const bool cok = (lane >= 4) && (lane < 60) && (w < WW);

    const float ths     = (float)ths_p[0];
    const float inv_tl1 = 1.0f / (TAUf * (ths * 0.1f));
    const float inv_l2  = 1.0f / (ths * 0.15f);

    // rings (k-slot indexed)
    float u0[4], u1[4], u2[4], u3[4];          // u rows (slot = (row-(R0-4))&3)
    float i0r[2], i1r[2];                      // i rows
    float sA[4], tA0[4], tA1[4];               // s,t iter-1
    float x2p[4], r20p[4], r21p[4], yr[4];     // stashed x2',r2',y
    float v0[4], v1[4], v2[4], v3[4];          // u' rows
    float j0r[2], j1r[2];                      // i' rows
    float sB[4], tB0[4], tB1[4];               // s',t' iter-2
    #pragma unroll
    for (int q = 0; q < 4; ++q) {
        u0[q]=u1[q]=u2[q]=u3[q]=0.f; sA[q]=tA0[q]=tA1[q]=0.f;
        x2p[q]=r20p[q]=r21p[q]=yr[q]=0.f; v0[q]=v1[q]=v2[q]=v3[q]=0.f;
        sB[q]=tB0[q]=tB1[q]=0.f;
    }
    i0r[0]=i0r[1]=i1r[0]=i1r[1]=0.f; j0r[0]=j0r[1]=j1r[0]=j1r[1]=0.f;

    auto uload = [&](int row) -> uint2 {
        uint2 z; z.x = 0u; z.y = 0u;
        if (((unsigned)row) < (unsigned)HH && wok)
            z = *(const uint2*)(u_in + 4 * (size_t)(boff + row * WW + w));
        return z;
    };
    auto unpk = [&](int sl, uint2 raw) {
        __half2 lo = *(__half2*)&raw.x;
        __half2 hi = *(__half2*)&raw.y;
        u0[sl] = __low2float(lo); u1[sl] = __high2float(lo);
        u2[sl] = __low2float(hi); u3[sl] = __high2float(hi);
    };

    // ---- prologue ----
    uint2 pu; pu.x = 0u; pu.y = 0u;
    float py = 0.f, px2 = 0.f, pr0 = 0.f, pr1 = 0.f;
    if (MODE != 0) {
        unpk(2, uload(R0 - 6));
        unpk(3, uload(R0 - 5));
        pu = uload(R0 - 4);
    }
    {
        int row = R0 - 5; bool ok = (((unsigned)row) < (unsigned)HH) && wok;
        int idx = boff + row * WW + w;
        py = ok ? y[idx] : 0.f;
        if (MODE != 0) {
            px2 = ok ? cf(x2_in[idx]) : 0.f;
            __half2 rv = ok ? *(const __half2*)(r2_in + 2 * (size_t)idx)
                            : __floats2half2_rn(0.f, 0.f);
            pr0 = __low2float(rv); pr1 = __high2float(rv);
        }
    }

    constexpr int NSTEP  = (MODE == 2) ? (HS + 8) : (HS + 10);
    constexpr int KI_LO  = (MODE == 2) ? 1 : 0;
    constexpr int KS_LO  = (MODE == 2) ? 2 : 1;
    constexpr int KU1_LO = (MODE == 2) ? 5 : 4;
    constexpr int KI2_LO = (MODE == 2) ? 7 : 6;
    constexpr int KS2_LO = (MODE == 2) ? 8 : 7;

    #pragma unroll
    for (int k = 0; k < NSTEP; ++k) {
        const int r = R0 - 5 + k;

        // --- load/unpack u; prefetch scalars ---
        uint2 nu; nu.x = 0u; nu.y = 0u;
        if (MODE != 0) { unpk(k & 3, pu); if (k < NSTEP - 1) nu = uload(r + 2); }
        float yv = py, x2v = px2, r20v = pr0, r21v = pr1;
        if (k < NSTEP - 1) {
            int row = r + 1; bool ok = (((unsigned)row) < (unsigned)HH) && wok;
            int idx = boff + row * WW + w;
            py = ok ? y[idx] : 0.f;
            if (MODE != 0) {
                px2 = ok ? cf(x2_in[idx]) : 0.f;
                __half2 rv = ok ? *(const __half2*)(r2_in + 2 * (size_t)idx)
                                : __floats2half2_rn(0.f, 0.f);
                pr0 = __low2float(rv); pr1 = __high2float(rv);
            }
        }

        // --- i(r) = eps2_adj(u) ---
        if (MODE != 0 && k >= KI_LO) {
            if (((unsigned)r) < (unsigned)HH) {
                float hD = (r < HH - 1) ? 1.f : 0.f;
                float a = u1[(k - 1) & 3], c2 = u2[(k - 1) & 3];
                i0r[k & 1] = u0[(k - 1) & 3] - u0[k & 3] - SD(a) + mA * a;
                i1r[k & 1] = c2 - SD(c2) - hD * u3[(k - 1) & 3] + u3[(k - 2) & 3];
            } else { i0r[k & 1] = 0.f; i1r[k & 1] = 0.f; }
        }

        // --- s,t(r) iter-1; stash x2',r2',y ---
        if (k >= KS_LO) {
            int sl = k & 3;
            float sv = 0.f, t0v = 0.f, t1v = 0.f, x2n = 0.f, r0n = 0.f, r1n = 0.f;
            if (((unsigned)r) < (unsigned)HH) {
                if (MODE == 0) {
                    sv = yv; x2n = yv;       // iter0: x=y, r=0
                } else {
                    float hD = (r < HH - 1) ? 1.f : 0.f;
                    float i0c = i0r[k & 1], i1c = i1r[k & 1], i1u = i1r[(k - 1) & 1];
                    float i0l = SUp(i0c);
                    float na = TAUf * (mA * i0l - mB * i0c + i1u - hD * i1c);
                    float x = (x2v - na + TAUf * yv) * INV1PT;
                    float rr0 = r20v + TAUf * i0c, rr1 = r21v + TAUf * i1c;
                    float mag = sqrtf(rr0 * rr0 + rr1 * rr1) * inv_tl1;
                    float ri = 1.f / fmaxf(mag, 1.f);
                    float q0 = rr0 - rr0 * ri, q1 = rr1 - rr1 * ri;
                    sv = 2.f * x - x2v; t0v = 2.f * q0 - r20v; t1v = 2.f * q1 - r21v;
                    x2n = x2v + RHOf * (x - x2v);
                    r0n = r20v + RHOf * (q0 - r20v);
                    r1n = r21v + RHOf * (q1 - r21v);
                }
            }
            sA[sl] = sv; tA0[sl] = t0v; tA1[sl] = t1v;
            x2p[sl] = x2n; r20p[sl] = r0n; r21p[sl] = r1n; yr[sl] = yv;
        }

        // --- u'(r-2) iter-1 dual -> v ring ---
        if (k >= KU1_LO) {
            int so = k & 3, ro = r - 2;
            if (((unsigned)ro) < (unsigned)HH) {
                float hD = (ro < HH - 1) ? 1.f : 0.f, hD1 = (ro + 1 < HH - 1) ? 1.f : 0.f;
                float sc = sA[(k - 2) & 3], sd = sA[(k - 1) & 3];
                float su = sA[(k - 3) & 3], s2 = sA[k & 3];
                float t0c = tA0[(k - 2) & 3], t0u = tA0[(k - 3) & 3];
                float t1c = tA1[(k - 2) & 3], t1d = tA1[(k - 1) & 3];
                float sc_p = SD(sc), su_p = SD(su), sc_m = SUp(sc), sd_m = SUp(sd);
                float t0c_m = SUp(t0c), t1c_m = SUp(t1c);
                float v0c = mB * (sc_p - sc) - t0c;
                float v1c = hD * (sd - sc) - t1c;
                float v0u = mB * (su_p - su) - t0u;
                float v0l = (sc - sc_m) - t0c_m;
                float v1l = hD * (sd_m - sc_m) - t1c_m;
                float v1d = hD1 * (s2 - sd) - t1d;
                float G0 = v0c - v0u, G1 = mA * (v0c - v0l);
                float G2 = v1c - mA * v1l, G3 = hD * (v1d - v1c);
                float a0 = u0[(k - 3) & 3], a1 = u1[(k - 3) & 3];
                float a2 = u2[(k - 3) & 3], a3 = u3[(k - 3) & 3];
                float b0 = a0 + SIGMAf * G0, b1 = a1 + SIGMAf * G1;
                float b2 = a2 + SIGMAf * G2, b3 = a3 + SIGMAf * G3;
                float mag = sqrtf(b0 * b0 + b1 * b1 + b2 * b2 + b3 * b3) * inv_l2;
                float ui = 1.f / fmaxf(mag, 1.f);
                v0[so] = a0 + RHOf * (b0 * ui - a0);
                v1[so] = a1 + RHOf * (b1 * ui - a1);
                v2[so] = a2 + RHOf * (b2 * ui - a2);
                v3[so] = a3 + RHOf * (b3 * ui - a3);
            } else { v0[so] = v1[so] = v2[so] = v3[so] = 0.f; }
        }

        // --- i'(r-3) from u' ---
        if (k >= KI2_LO) {
            int r3 = r - 3;
            if (((unsigned)r3) < (unsigned)HH) {
                float hD = (r3 < HH - 1) ? 1.f : 0.f;
                float a = v1[(k - 1) & 3], c2 = v2[(k - 1) & 3];
                j0r[k & 1] = v0[(k - 1) & 3] - v0[k & 3] - SD(a) + mA * a;
                j1r[k & 1] = c2 - SD(c2) - hD * v3[(k - 1) & 3] + v3[(k - 2) & 3];
            } else { j0r[k & 1] = 0.f; j1r[k & 1] = 0.f; }
        }

        // --- s',t'(r-3) iter-2; write x2'',r2'' (or xout) on core rows ---
        if (k >= KS2_LO) {
            int r3 = r - 3, sl = k & 3, xs = (k - 3) & 3;
            float sv = 0.f, t0v = 0.f, t1v = 0.f;
            if (((unsigned)r3) < (unsigned)HH) {
                float hD = (r3 < HH - 1) ? 1.f : 0.f;
                float i0c = j0r[k & 1], i1c = j1r[k & 1], i1u = j1r[(k - 1) & 1];
                float i0l = SUp(i0c);
                float na = TAUf * (mA * i0l - mB * i0c + i1u - hD * i1c);
                float yv2 = yr[xs], x2v2 = x2p[xs];
                float x = (x2v2 - na + TAUf * yv2) * INV1PT;
                if (MODE == 2) {
                    if (k >= 8 && k <= HS + 7) {
                        if (cok) xout[boff + r3 * WW + w] = x2v2 + RHOf * (x - x2v2);
                    }
                } else {
                    float r20v2 = r20p[xs], r21v2 = r21p[xs];
                    float rr0 = r20v2 + TAUf * i0c, rr1 = r21v2 + TAUf * i1c;
                    float mag = sqrtf(rr0 * rr0 + rr1 * rr1) * inv_tl1;
                    float ri = 1.f / fmaxf(mag, 1.f);
                    float q0 = rr0 - rr0 * ri, q1 = rr1 - rr1 * ri;
                    sv = 2.f * x - x2v2; t0v = 2.f * q0 - r20v2; t1v = 2.f * q1 - r21v2;
                    if (k >= 8 && k <= HS + 7) {
                        if (cok) {
                            int idx = boff + r3 * WW + w;
                            x2_out[idx] = __float2half(x2v2 + RHOf * (x - x2v2));
                            *(__half2*)(r2_out + 2 * (size_t)idx) = __floats2half2_rn(
                                r20v2 + RHOf * (q0 - r20v2), r21v2 + RHOf * (q1 - r21v2));
                        }
                    }
                }
            }
            if (MODE != 2) { sB[sl] = sv; tB0[sl] = t0v; tB1[sl] = t1v; }
        }

        // --- u''(r-5) iter-2 dual -> global ---
        if (MODE != 2 && k >= 10) {
            int ro = r - 5;  // in [R0, R0+HS-1], always in-image
            float hD = (ro < HH - 1) ? 1.f : 0.f, hD1 = (ro + 1 < HH - 1) ? 1.f : 0.f;
            float sc = sB[(k - 2) & 3], sd = sB[(k - 1) & 3];
            float su = sB[(k - 3) & 3], s2 = sB[k & 3];
            float t0c = tB0[(k - 2) & 3], t0u = tB0[(k - 3) & 3];
            float t1c = tB1[(k - 2) & 3], t1d = tB1[(k - 1) & 3];
            float sc_p = SD(sc), su_p = SD(su), sc_m = SUp(sc), sd_m = SUp(sd);
            float t0c_m = SUp(t0c), t1c_m = SUp(t1c);
            float v0c = mB * (sc_p - sc) - t0c;
            float v1c = hD * (sd - sc) - t1c;
            float v0u = mB * (su_p - su) - t0u;
            float v0l = (sc - sc_m) - t0c_m;
            float v1l = hD * (sd_m - sc_m) - t1c_m;
            float v1d = hD1 * (s2 - sd) - t1d;
            float G0 = v0c - v0u, G1 = mA * (v0c - v0l);
            float G2 = v1c - mA * v1l, G3 = hD * (v1d - v1c);
            float a0 = v0[(k - 3) & 3], a1 = v1[(k - 3) & 3];
            float a2 = v2[(k - 3) & 3], a3 = v3[(k - 3) & 3];
            float b0 = a0 + SIGMAf * G0, b1 = a1 + SIGMAf * G1;
            float b2 = a2 + SIGMAf * G2, b3 = a3 + SIGMAf * G3;
            float mag = sqrtf(b0 * b0 + b1 * b1 + b2 * b2 + b3 * b3) * inv_l2;
            float ui = 1.f / fmaxf(mag, 1.f);
            if (cok) {
                int idx = boff + ro * WW + w;
                __half2 lo = __floats2half2_rn(a0 + RHOf * (b0 * ui - a0),
                                               a1 + RHOf * (b1 * ui - a1));
                __half2 hi = __floats2half2_rn(a2 + RHOf * (b2 * ui - a2),
                                               a3 + RHOf * (b3 * ui - a3));
                uint2 st; st.x = *(unsigned*)&lo; st.y = *(unsigned*)&hi;
                *(uint2*)(u_out + 4 * (size_t)idx) = st;
            }
        }

        if (MODE != 0) pu = nu;
    }
}

extern "C" void kernel_launch(void* const* d_in, const int* in_sizes, int n_in,
                              void* d_out, int out_size, void* d_ws, size_t ws_size,
                              hipStream_t stream)
{
    const float* y   = (const float*)d_in[0];
    const int*   ths = (const int*)d_in[1];
    __half* ws = (__half*)d_ws;

    __half* Ax2 = ws;
    __half* Ar2 = ws + (size_t)NPIX;
    __half* Au  = ws + (size_t)3 * NPIX;
    __half* Bx2 = ws + (size_t)7 * NPIX;
    __half* Br2 = ws + (size_t)8 * NPIX;
    __half* Bu  = ws + (size_t)10 * NPIX;
    float*  xout = (float*)d_out;

    dim3 block(256);
    dim3 grid(NBLK);

    // iters 0+1 -> B
    sweep2<0><<<grid, block, 0, stream>>>(y, ths, Ax2, Ar2, Au, Bx2, Br2, Bu, nullptr);
    // iters 2+3: B -> A
    sweep2<1><<<grid, block, 0, stream>>>(y, ths, Bx2, Br2, Bu, Ax2, Ar2, Au, nullptr);
    // iters 4+5: A -> B
    sweep2<1><<<grid, block, 0, stream>>>(y, ths, Ax2, Ar2, Au, Bx2, Br2, Bu, nullptr);
    // iters 6+7: B -> A
    sweep2<1><<<grid, block, 0, stream>>>(y, ths, Bx2, Br2, Bu, Ax2, Ar2, Au, nullptr);
    // iters 8+9: A -> xout (f32)
    sweep2<2><<<grid, block, 0, stream>>>(y, ths, Ax2, Ar2, Au, nullptr, nullptr, nullptr, xout);
}

// Round 11
// 187.519 us; speedup vs baseline: 1.1189x; 1.1189x over previous
//
#include <hip/hip_runtime.h>
#include <hip/hip_fp16.h>
#include <math.h>

#define HH 512
#define WW 512
#define BB 4
#define NPIX (BB * HH * WW)

#define HS 4                  // core rows per wave
#define NSX 9                 // strips of 60 core cols
#define NBAND (HH / HS)       // 128
#define NWAVES (NSX * NBAND * BB)   // 4608
#define NBLK (NWAVES / 4)           // 1152

constexpr float TAUf   = 0.01f;
constexpr float RHOf   = 1.99f;
constexpr float SIGMAf = (float)(1.0 / 0.01 / 72.0);
constexpr float INV1PT = (float)(1.0 / 1.01);

__device__ __forceinline__ float cf(__half h) { return __half2float(h); }
__device__ __forceinline__ float SD(float v)  { return __shfl_down(v, 1, 64); }
__device__ __forceinline__ float SUp(float v) { return __shfl_up(v, 1, 64); }
__device__ __forceinline__ unsigned SDu(unsigned v) {
    return (unsigned)__shfl_down((int)v, 1, 64);
}
__device__ __forceinline__ float2 h2f(unsigned v) {
    __half2 h = *reinterpret_cast<__half2*>(&v);
    return make_float2(__low2float(h), __high2float(h));
}

// Fully-skewed register pipeline, one primal-dual iteration per launch.
// Step k stages (all consume only prior-step ring data):
//   u''-store row R0+k-8 | i row R0+k-3 | s,t row R0+k-4 | v row R0+k-6
//   raw-u load row R0+k (2-step lead) | scalar load row R0+k-2 (2-step lead)
// MODE: 0 = iter0 (x=y, r=0, u=0); 1 = mid; 2 = last (x-only, f32 out)
template <int MODE>
__global__ __launch_bounds__(256) void sweep(
    const float* __restrict__ y, const int* __restrict__ ths_p,
    const __half* __restrict__ x2_in, const __half* __restrict__ r2_in,
    const __half* __restrict__ u_in,
    __half* __restrict__ x2_out, __half* __restrict__ r2_out,
    __half* __restrict__ u_out, float* __restrict__ xout)
{
    const int tid  = threadIdx.x;
    const int lane = tid & 63;
    const int wid  = blockIdx.x * 4 + (tid >> 6);
    const int sx   = wid % NSX;
    const int t2   = wid / NSX;
    const int band = t2 & (NBAND - 1);
    const int b    = t2 / NBAND;
    const int R0   = band * HS;
    const int w    = sx * 60 - 2 + lane;
    const int boff = b * (HH * WW);
    const bool wok = ((unsigned)w) < (unsigned)WW;
    const float mA = (w >= 1 && w < WW) ? 1.f : 0.f;
    const float mB = (w >= 0 && w < WW - 1) ? 1.f : 0.f;
    const bool cok = (lane >= 2) && (lane < 62) && (w < WW);

    const float ths     = (float)ths_p[0];
    const float inv_tl1 = 1.0f / (TAUf * (ths * 0.1f));
    const float inv_l2  = 1.0f / (ths * 0.15f);

    // rings (slot expressions fold to constants under full unroll)
    uint2 araw[8];                       // raw u rows; slot(row)=(row-R0+4)&7
    float sqy[2], sqx[2], sqr0[2], sqr1[2];
    float i0r[4], i1r[4];
    float srg[4], t0rg[4], t1rg[4];
    float v0rg[4], v1rg[4];
    #pragma unroll
    for (int q = 0; q < 4; ++q) {
        i0r[q]=i1r[q]=srg[q]=t0rg[q]=t1rg[q]=v0rg[q]=v1rg[q]=0.f;
    }
    #pragma unroll
    for (int q = 0; q < 8; ++q) { araw[q].x = 0u; araw[q].y = 0u; }
    sqy[0]=sqy[1]=sqx[0]=sqx[1]=sqr0[0]=sqr0[1]=sqr1[0]=sqr1[1]=0.f;

    auto uload = [&](int row) -> uint2 {
        uint2 z; z.x = 0u; z.y = 0u;
        if (((unsigned)row) < (unsigned)HH && wok)
            z = *(const uint2*)(u_in + 4 * (size_t)(boff + row * WW + w));
        return z;
    };

    // prologue: raw rows R0-3..R0-1 -> slots 1..3
    if (MODE != 0) {
        araw[1] = uload(R0 - 3);
        araw[2] = uload(R0 - 2);
        araw[3] = uload(R0 - 1);
    }

    constexpr int NSTEP  = (MODE == 2) ? (HS + 4) : (HS + 8);
    constexpr int KI_LO  = (MODE == 2) ? 2 : 1;
    constexpr int KI_HI  = (MODE == 2) ? (HS + 2) : (HS + 4);
    constexpr int KS_LO  = (MODE == 2) ? 4 : 3;
    constexpr int KS_HI  = (MODE == 2) ? (HS + 3) : (HS + 5);
    constexpr int KA_HI  = (MODE == 2) ? HS : (HS + 2);

    #pragma unroll
    for (int k = 0; k < NSTEP; ++k) {

        // ---- u''-stage: row ro = R0+k-8 (reads old araw slot before reload) ----
        if (MODE != 2 && k >= 8) {
            const int ro = R0 + k - 8;   // core row, always in-image
            float a0, a1, a2, a3;
            if (MODE == 0) { a0 = a1 = a2 = a3 = 0.f; }
            else {
                uint2 rr_ = araw[(k - 4) & 7];
                float2 p = h2f(rr_.x), q = h2f(rr_.y);
                a0 = p.x; a1 = p.y; a2 = q.x; a3 = q.y;
            }
            float v0c = v0rg[(k - 2) & 3], v0u = v0rg[(k - 3) & 3];
            float v1c = v1rg[(k - 2) & 3], v1d = v1rg[(k - 1) & 3];
            float hD = (ro < HH - 1) ? 1.f : 0.f;
            float G0 = v0c - v0u;
            float G1 = mA * (v0c - SUp(v0c));
            float G2 = v1c - mA * SUp(v1c);
            float G3 = hD * (v1d - v1c);
            float b0 = a0 + SIGMAf * G0, b1 = a1 + SIGMAf * G1;
            float b2 = a2 + SIGMAf * G2, b3 = a3 + SIGMAf * G3;
            float mag = sqrtf(b0 * b0 + b1 * b1 + b2 * b2 + b3 * b3) * inv_l2;
            float ui = 1.f / fmaxf(mag, 1.f);
            if (cok) {
                int idx = boff + ro * WW + w;
                __half2 lo = __floats2half2_rn(a0 + RHOf * (b0 * ui - a0),
                                               a1 + RHOf * (b1 * ui - a1));
                __half2 hi = __floats2half2_rn(a2 + RHOf * (b2 * ui - a2),
                                               a3 + RHOf * (b3 * ui - a3));
                uint2 st; st.x = *(unsigned*)&lo; st.y = *(unsigned*)&hi;
                *(uint2*)(u_out + 4 * (size_t)idx) = st;
            }
        }

        // ---- i-stage: row ri = R0+k-3 (raw rows loaded >=2 steps ago) ----
        if (MODE != 0 && k >= KI_LO && k <= KI_HI) {
            const int ri = R0 + k - 3;
            if (((unsigned)ri) < (unsigned)HH) {
                uint2 rc = araw[(k + 1) & 7];   // row ri
                uint2 rd = araw[(k + 2) & 7];   // row ri+1
                uint2 ru = araw[(k) & 7];       // row ri-1
                float2 c01 = h2f(rc.x), c23 = h2f(rc.y);
                float2 d01 = h2f(rd.x);
                float2 u23 = h2f(ru.y);
                float2 s01 = h2f(SDu(rc.x));    // u0,u1 at lane+1
                float2 s23 = h2f(SDu(rc.y));    // u2,u3 at lane+1
                float hD = (ri < HH - 1) ? 1.f : 0.f;
                i0r[k & 3] = c01.x - d01.x - s01.y + mA * c01.y;
                i1r[k & 3] = c23.x - s23.x - hD * c23.y + u23.y;
            } else { i0r[k & 3] = 0.f; i1r[k & 3] = 0.f; }
        }

        // ---- s,t-stage: row rs = R0+k-4 (i from steps k-1,k-2; scalars lead 2) ----
        if (k >= KS_LO && k <= KS_HI) {
            const int rs = R0 + k - 4;
            const bool coreRow = (k >= 4) && (k <= HS + 3);
            float sv = 0.f, t0v = 0.f, t1v = 0.f;
            if (((unsigned)rs) < (unsigned)HH) {
                float yv = sqy[0];
                if (MODE == 0) {
                    sv = yv;
                    if (coreRow && cok) {
                        int idx = boff + rs * WW + w;
                        x2_out[idx] = __float2half(yv);
                        *(__half2*)(r2_out + 2 * (size_t)idx) =
                            __floats2half2_rn(0.f, 0.f);
                    }
                } else {
                    float i0c = i0r[(k - 1) & 3], i1c = i1r[(k - 1) & 3];
                    float i1u = i1r[(k - 2) & 3];
                    float i0l = SUp(i0c);
                    float hD = (rs < HH - 1) ? 1.f : 0.f;
                    float na = TAUf * (mA * i0l - mB * i0c + i1u - hD * i1c);
                    float x2v = sqx[0];
                    float x = (x2v - na + TAUf * yv) * INV1PT;
                    if (MODE == 2) {
                        if (coreRow && cok)
                            xout[boff + rs * WW + w] = x2v + RHOf * (x - x2v);
                    } else {
                        float r20v = sqr0[0], r21v = sqr1[0];
                        float rr0 = r20v + TAUf * i0c, rr1 = r21v + TAUf * i1c;
                        float mag = sqrtf(rr0 * rr0 + rr1 * rr1) * inv_tl1;
                        float ri_ = 1.f / fmaxf(mag, 1.f);
                        float q0 = rr0 - rr0 * ri_, q1 = rr1 - rr1 * ri_;
                        sv = 2.f * x - x2v;
                        t0v = 2.f * q0 - r20v;
                        t1v = 2.f * q1 - r21v;
                        if (coreRow && cok) {
                            int idx = boff + rs * WW + w;
                            x2_out[idx] = __float2half(x2v + RHOf * (x - x2v));
                            *(__half2*)(r2_out + 2 * (size_t)idx) = __floats2half2_rn(
                                r20v + RHOf * (q0 - r20v), r21v + RHOf * (q1 - r21v));
                        }
                    }
                }
            }
            if (MODE != 2) { srg[k & 3] = sv; t0rg[k & 3] = t0v; t1rg[k & 3] = t1v; }
        }

        // ---- v-stage: row rv = R0+k-6 (s from steps k-2, k-1) ----
        if (MODE != 2 && k >= 5 && k <= HS + 6) {
            const int rv = R0 + k - 6;
            float v0 = 0.f, v1 = 0.f;
            if (((unsigned)rv) < (unsigned)HH) {
                float sc = srg[(k - 2) & 3];    // s(rv)
                float sn = srg[(k - 1) & 3];    // s(rv+1)
                float t0c = t0rg[(k - 2) & 3], t1c = t1rg[(k - 2) & 3];
                float hD = (rv < HH - 1) ? 1.f : 0.f;
                v0 = mB * (SD(sc) - sc) - t0c;
                v1 = hD * (sn - sc) - t1c;
            }
            v0rg[k & 3] = v0;
            v1rg[k & 3] = v1;
        }

        // ---- queue shift + loads (after all consumers) ----
        sqy[0] = sqy[1]; sqx[0] = sqx[1]; sqr0[0] = sqr0[1]; sqr1[0] = sqr1[1];
        if (k <= KS_HI - 2) {
            int row = R0 + k - 2;
            bool ok = (((unsigned)row) < (unsigned)HH) && wok;
            int idx = boff + row * WW + w;
            sqy[1] = ok ? y[idx] : 0.f;
            if (MODE != 0) {
                sqx[1] = ok ? cf(x2_in[idx]) : 0.f;
                if (MODE == 1) {
                    __half2 rv = ok ? *(const __half2*)(r2_in + 2 * (size_t)idx)
                                    : __floats2half2_rn(0.f, 0.f);
                    sqr0[1] = __low2float(rv); sqr1[1] = __high2float(rv);
                }
            }
        }
        if (MODE != 0 && k <= KA_HI) {
            araw[(k + 4) & 7] = uload(R0 + k);
        }
    }
}

extern "C" void kernel_launch(void* const* d_in, const int* in_sizes, int n_in,
                              void* d_out, int out_size, void* d_ws, size_t ws_size,
                              hipStream_t stream)
{
    const float* y   = (const float*)d_in[0];
    const int*   ths = (const int*)d_in[1];
    __half* ws = (__half*)d_ws;

    __half* Ax2 = ws;
    __half* Ar2 = ws + (size_t)NPIX;
    __half* Au  = ws + (size_t)3 * NPIX;
    __half* Bx2 = ws + (size_t)7 * NPIX;
    __half* Br2 = ws + (size_t)8 * NPIX;
    __half* Bu  = ws + (size_t)10 * NPIX;
    float*  xout = (float*)d_out;

    dim3 block(256);
    dim3 grid(NBLK);

    // iter 0 (analytic) -> B
    sweep<0><<<grid, block, 0, stream>>>(y, ths, Ax2, Ar2, Au, Bx2, Br2, Bu, nullptr);
    // iters 1..8 alternate
    __half *ix2 = Bx2, *ir2 = Br2, *iu = Bu;
    __half *ox2 = Ax2, *or2 = Ar2, *ou = Au;
    for (int it = 1; it <= 8; ++it) {
        sweep<1><<<grid, block, 0, stream>>>(y, ths, ix2, ir2, iu, ox2, or2, ou, nullptr);
        __half* t;
        t = ix2; ix2 = ox2; ox2 = t;
        t = ir2; ir2 = or2; or2 = t;
        t = iu;  iu  = ou;  ou  = t;
    }
    // iter 9: x only -> d_out
    sweep<2><<<grid, block, 0, stream>>>(y, ths, ix2, ir2, iu, nullptr, nullptr, nullptr, xout);
}